// Round 2
// baseline (1164.528 us; speedup 1.0000x reference)
//
#include <hip/hip_runtime.h>

#define B_   8
#define C_   512
#define HW_  2304
#define BM   128
#define BN   128
#define BKQ  32              // K-step (elements); row = 64 B
#define NKS  (C_ / BKQ)      // 16
#define NT_  (HW_ / BN)      // 18
#define MT_PER_BLOCK 3
#define MCHUNKS 6            // 18 m-tiles / 3
#define NSTEPS (MT_PER_BLOCK * NKS)   // 48 pipeline steps per block

typedef __bf16 bf16x8 __attribute__((ext_vector_type(8)));
typedef float  f32x4  __attribute__((ext_vector_type(4)));

__device__ __forceinline__ unsigned short f2bf(float f) {
  unsigned int u = __float_as_uint(f);
  u += 0x7FFF + ((u >> 16) & 1);   // round-to-nearest-even
  return (unsigned short)(u >> 16);
}

__device__ __forceinline__ void gload_lds16(const void* g, void* l) {
  __builtin_amdgcn_global_load_lds(
      (const __attribute__((address_space(1))) unsigned int*)g,
      (__attribute__((address_space(3))) unsigned int*)l, 16, 0, 0);
}

__global__ void zero_out(float* __restrict__ out, int n) {
  int i = blockIdx.x * 256 + threadIdx.x;
  if (i < n) out[i] = 0.0f;
}

// Fused: key fp32 [b][c][n] -> keyT bf16 [b][n][c], plus coarse partial dots
// (fp32, atomicAdd into pre-zeroed out channels 4..9).
__global__ void transpose_coarse(const float* __restrict__ key,
                                 const float* __restrict__ v0, const float* __restrict__ v1,
                                 const float* __restrict__ v2, const float* __restrict__ v3,
                                 const float* __restrict__ v4, const float* __restrict__ v5,
                                 unsigned short* __restrict__ keyT,
                                 float* __restrict__ out) {
  __shared__ float tile[32][33];
  __shared__ float red2[6][8][32];
  int b  = blockIdx.z;
  int n0 = blockIdx.x * 32;
  int c0 = blockIdx.y * 32;
  int tx = threadIdx.x;  // 0..31
  int ty = threadIdx.y;  // 0..7
#pragma unroll
  for (int i = 0; i < 4; i++) {
    int c = c0 + ty + i * 8;
    tile[ty + i * 8][tx] = key[(size_t)b * C_ * HW_ + (size_t)c * HW_ + n0 + tx];
  }
  __syncthreads();
#pragma unroll
  for (int i = 0; i < 4; i++) {
    int n = n0 + ty + i * 8;
    keyT[(size_t)b * HW_ * C_ + (size_t)n * C_ + c0 + tx] = f2bf(tile[tx][ty + i * 8]);
  }
  // coarse partials: thread covers n = n0+tx, c-range = c0 + ty*4 .. +4
  float s[6] = {0.f, 0.f, 0.f, 0.f, 0.f, 0.f};
#pragma unroll
  for (int i = 0; i < 4; i++) {
    int cr = ty * 4 + i;
    int c  = c0 + cr;
    float kv = tile[cr][tx];
    s[0] += v0[b * C_ + c] * kv;
    s[1] += v1[b * C_ + c] * kv;
    s[2] += v2[b * C_ + c] * kv;
    s[3] += v3[b * C_ + c] * kv;
    s[4] += v4[b * C_ + c] * kv;
    s[5] += v5[b * C_ + c] * kv;
  }
#pragma unroll
  for (int j = 0; j < 6; j++) red2[j][ty][tx] = s[j];
  __syncthreads();
  if (ty < 6) {
    float a = 0.f;
#pragma unroll
    for (int k = 0; k < 8; k++) a += red2[ty][k][tx];
    atomicAdd(&out[((size_t)b * 10 + 4 + ty) * HW_ + n0 + tx], a);
  }
}

// 4 fine banks fp32 [b][m][c] -> bf16 stacked [g][b][m][c]
__global__ void convert_banks(const float* __restrict__ b0, const float* __restrict__ b1,
                              const float* __restrict__ b2, const float* __restrict__ b3,
                              unsigned short* __restrict__ out) {
  const size_t per = (size_t)B_ * HW_ * C_;
  int g = blockIdx.y;
  const float* src = (g == 0) ? b0 : (g == 1) ? b1 : (g == 2) ? b2 : b3;
  size_t i = ((size_t)blockIdx.x * blockDim.x + threadIdx.x) * 4;
  float4 v = *(const float4*)(src + i);
  ushort4 o;
  o.x = f2bf(v.x); o.y = f2bf(v.y); o.z = f2bf(v.z); o.w = f2bf(v.w);
  *(ushort4*)(out + g * per + i) = o;
}

// Fine scores, bank-paired. XCD-pinned decode (b = lin & 7).
// K-loop: depth-2 pipeline, double-buffered LDS, raw s_barrier + counted
// s_waitcnt vmcnt(6) — no vmcnt(0) drain in the main loop (T3+T4). Loads
// for step s+2 are issued right after the buffer for step s is consumed,
// giving every staged tile a two-step (~2x compute) latency window.
__global__ __launch_bounds__(256, 3) void fine_kernel(
    const unsigned short* __restrict__ keyT,   // bf16 [b][n][c]
    const unsigned short* __restrict__ banks,  // bf16 [g][b][m][c]
    const float* __restrict__ sds,             // fp32 [b][m][n]
    float* __restrict__ pmax) {
  int lin = blockIdx.x;
  int b   = lin & 7;               // XCD-pinned batch
  int ix  = lin >> 3;              // 0..215
  int gp  = (ix >= 108) ? 1 : 0;   // 0: banks 0,1 (unmasked)  1: banks 2,3 (masked)
  int w   = ix - gp * 108;         // 0..107
  int mc  = w / NT_;               // 0..5  (mc-major for A reuse in L2)
  int nt  = w % NT_;
  int n0  = nt * BN;

  __shared__ __align__(16) unsigned short sbuf[2][3][BM * BKQ];  // 48 KB dbuf
  __shared__ float red[4 * BN];

  int t    = threadIdx.x;
  int wave = t >> 6;
  int lane = t & 63;
  int quad = lane >> 4;
  int l15  = lane & 15;
  int wm   = (wave & 1) * 64;
  int wn   = (wave >> 1) * 64;

  // staging: lane writes LDS row (rbase + lane>>2), 16B slot (lane&3).
  // source pre-swizzle so read slot = quad ^ ((row>>1)&3) returns chunk quad.
  int ksub = (lane & 3) ^ ((lane >> 3) & 3);   // global 8-elem chunk for this lane
  int swo  = (quad ^ ((l15 >> 1) & 3)) * 8;    // fragment-read element offset

  const unsigned short* bank0 = banks + ((size_t)(2 * gp) * B_ + b) * (size_t)HW_ * C_;
  const unsigned short* bank1 = banks + ((size_t)(2 * gp + 1) * B_ + b) * (size_t)HW_ * C_;
  const unsigned short* keyb  = keyT + (size_t)b * HW_ * C_;
  const float* maskb = sds + (size_t)b * HW_ * HW_;
  const bool masked = (gp == 1);

  // stage step s (s = mi*16+kc) into buffer P. 6 gload_lds per wave.
  auto STAGE = [&](int P, int s) {
    int mi  = s >> 4;
    int kc  = s & 15;
    int m0s = (mc * MT_PER_BLOCK + mi) * BM;
    unsigned short* A0d = &sbuf[P][0][0];
    unsigned short* A1d = &sbuf[P][1][0];
    unsigned short* Bd  = &sbuf[P][2][0];
#pragma unroll
    for (int j = 0; j < 2; j++) {
      int rbase = j * 64 + wave * 16;                       // wave-uniform LDS row base
      size_t go = (size_t)(rbase + (lane >> 2)) * C_ + (size_t)kc * BKQ + ksub * 8;
      gload_lds16(bank0 + (size_t)m0s * C_ + go, &A0d[rbase * BKQ]);
      gload_lds16(bank1 + (size_t)m0s * C_ + go, &A1d[rbase * BKQ]);
      gload_lds16(keyb  + (size_t)n0  * C_ + go, &Bd [rbase * BKQ]);
    }
  };

  float rm0[4], rm1[4];
#pragma unroll
  for (int i = 0; i < 4; i++) { rm0[i] = -3.4e38f; rm1[i] = -3.4e38f; }

  f32x4 acc0[4][4], acc1[4][4];

  // one pipeline step; P must be a literal (LDS read addressing static).
#define KSTEP(P, MI, KC)                                                       \
  do {                                                                         \
    int s_ = (MI) * 16 + (KC);                                                 \
    if (s_ < NSTEPS - 2) asm volatile("s_waitcnt vmcnt(6)" ::: "memory");      \
    else                 asm volatile("s_waitcnt vmcnt(0)" ::: "memory");      \
    __builtin_amdgcn_s_barrier();            /* buf[P] fully staged */         \
    __builtin_amdgcn_sched_barrier(0);                                         \
    const unsigned short* A0s = &sbuf[P][0][0];                                \
    const unsigned short* A1s = &sbuf[P][1][0];                                \
    const unsigned short* Bs  = &sbuf[P][2][0];                                \
    bf16x8 a0[4], a1[4], bb[4];                                                \
    _Pragma("unroll") for (int ms = 0; ms < 4; ms++) {                         \
      a0[ms] = *(const bf16x8*)(&A0s[(wm + ms * 16 + l15) * BKQ + swo]);       \
      a1[ms] = *(const bf16x8*)(&A1s[(wm + ms * 16 + l15) * BKQ + swo]);       \
    }                                                                          \
    _Pragma("unroll") for (int ns = 0; ns < 4; ns++)                           \
      bb[ns] = *(const bf16x8*)(&Bs[(wn + ns * 16 + l15) * BKQ + swo]);        \
    asm volatile("s_waitcnt lgkmcnt(0)" ::: "memory");                         \
    __builtin_amdgcn_sched_barrier(0);                                         \
    __builtin_amdgcn_s_barrier();            /* all waves done reading P */    \
    __builtin_amdgcn_sched_barrier(0);                                         \
    if (s_ + 2 < NSTEPS) STAGE(P, s_ + 2);   /* overwrite P for step s+2 */    \
    __builtin_amdgcn_s_setprio(1);                                             \
    _Pragma("unroll") for (int ms = 0; ms < 4; ms++)                           \
      _Pragma("unroll") for (int ns = 0; ns < 4; ns++) {                       \
        acc0[ms][ns] = __builtin_amdgcn_mfma_f32_16x16x32_bf16(                \
            a0[ms], bb[ns], acc0[ms][ns], 0, 0, 0);                            \
        acc1[ms][ns] = __builtin_amdgcn_mfma_f32_16x16x32_bf16(                \
            a1[ms], bb[ns], acc1[ms][ns], 0, 0, 0);                            \
      }                                                                        \
    __builtin_amdgcn_s_setprio(0);                                             \
  } while (0)

  // prologue: fill both pipeline slots
  STAGE(0, 0);
  STAGE(1, 1);

  for (int mi = 0; mi < MT_PER_BLOCK; mi++) {
#pragma unroll
    for (int i = 0; i < 4; i++)
#pragma unroll
      for (int j = 0; j < 4; j++)
#pragma unroll
        for (int e = 0; e < 4; e++) { acc0[i][j][e] = 0.0f; acc1[i][j][e] = 0.0f; }

    for (int kc2 = 0; kc2 < NKS; kc2 += 2) {
      KSTEP(0, mi, kc2);
      KSTEP(1, mi, kc2 + 1);
    }

    int m0 = (mc * MT_PER_BLOCK + mi) * BM;
    // epilogue (registers + mask global loads only; pipeline stages for the
    // next m-tile are already in flight underneath)
    // lane holds S[m0+wm+ms*16+quad*4+r][n0+wn+ns*16+l15]
#pragma unroll
    for (int ms = 0; ms < 4; ms++) {
#pragma unroll
      for (int ns = 0; ns < 4; ns++) {
        int n = n0 + wn + ns * 16 + l15;
#pragma unroll
        for (int r = 0; r < 4; r++) {
          int m = m0 + wm + ms * 16 + quad * 4 + r;
          float s0 = acc0[ms][ns][r];
          float s1 = acc1[ms][ns][r];
          if (masked) {
            float w_ = maskb[(size_t)m * HW_ + n];   // one load, two uses
            s0 *= w_; s1 *= w_;
          }
          rm0[ns] = fmaxf(rm0[ns], s0);
          rm1[ns] = fmaxf(rm1[ns], s1);
        }
      }
    }
  }
#undef KSTEP

  // reduce across quads (same column, different m rows)
#pragma unroll
  for (int ns = 0; ns < 4; ns++) {
    float v = rm0[ns];
    v = fmaxf(v, __shfl_xor(v, 16, 64));
    v = fmaxf(v, __shfl_xor(v, 32, 64));
    rm0[ns] = v;
    float u = rm1[ns];
    u = fmaxf(u, __shfl_xor(u, 16, 64));
    u = fmaxf(u, __shfl_xor(u, 32, 64));
    rm1[ns] = u;
  }
  if (lane < 16) {
#pragma unroll
    for (int ns = 0; ns < 4; ns++) {
      red[(wave & 1) * BN + wn + ns * 16 + l15]           = rm0[ns];
      red[2 * BN + (wave & 1) * BN + wn + ns * 16 + l15]  = rm1[ns];
    }
  }
  __syncthreads();
  if (t < BN) {
    float vv0 = fmaxf(red[t], red[BN + t]);
    float vv1 = fmaxf(red[2 * BN + t], red[3 * BN + t]);
    pmax[(((size_t)mc * B_ + b) * 4 + 2 * gp)     * HW_ + n0 + t] = vv0;
    pmax[(((size_t)mc * B_ + b) * 4 + 2 * gp + 1) * HW_ + n0 + t] = vv1;
  }
}

// max over m-chunks -> out channels 0..3
__global__ void fine_combine(const float* __restrict__ pmax, float* __restrict__ out) {
  int i = blockIdx.x * 256 + threadIdx.x;   // over B_*4*HW_
  if (i >= B_ * 4 * HW_) return;
  int n = i % HW_;
  int g = (i / HW_) % 4;
  int b = i / (HW_ * 4);
  float v = -3.4e38f;
#pragma unroll
  for (int mc = 0; mc < MCHUNKS; mc++)
    v = fmaxf(v, pmax[(((size_t)mc * B_ + b) * 4 + g) * HW_ + n]);
  out[((size_t)b * 10 + g) * HW_ + n] = v;
}

extern "C" void kernel_launch(void* const* d_in, const int* in_sizes, int n_in,
                              void* d_out, int out_size, void* d_ws, size_t ws_size,
                              hipStream_t stream) {
  const float* key  = (const float*)d_in[0];
  const float* sds  = (const float*)d_in[1];
  const float* gbg  = (const float*)d_in[2];
  const float* gfg  = (const float*)d_in[3];
  const float* lbg  = (const float*)d_in[4];
  const float* lfg  = (const float*)d_in[5];
  const float* obg  = (const float*)d_in[6];
  const float* ofg  = (const float*)d_in[7];
  const float* sbg  = (const float*)d_in[8];
  const float* sfg  = (const float*)d_in[9];
  const float* lobg = (const float*)d_in[10];
  const float* lofg = (const float*)d_in[11];
  float* out = (float*)d_out;

  unsigned short* keyT  = (unsigned short*)d_ws;               // 18.9 MB
  unsigned short* banks = keyT + (size_t)B_ * HW_ * C_;        // +75.5 MB
  float* pmax = (float*)(banks + (size_t)4 * B_ * HW_ * C_);   // +1.77 MB

  zero_out<<<(out_size + 255) / 256, 256, 0, stream>>>(out, out_size);
  convert_banks<<<dim3((B_ * HW_ * C_) / (4 * 256), 4), 256, 0, stream>>>(gbg, gfg, lbg, lfg, banks);
  transpose_coarse<<<dim3(HW_ / 32, C_ / 32, B_), dim3(32, 8), 0, stream>>>(
      key, obg, ofg, sbg, sfg, lobg, lofg, keyT, out);
  fine_kernel<<<dim3(NT_ * MCHUNKS * 2 * B_), 256, 0, stream>>>(keyT, banks, sds, pmax);
  fine_combine<<<(B_ * 4 * HW_ + 255) / 256, 256, 0, stream>>>(pmax, out);
}

// Round 4
// 851.413 us; speedup vs baseline: 1.3678x; 1.3678x over previous
//
#include <hip/hip_runtime.h>

#define B_   8
#define C_   512
#define HW_  2304
#define BM   128
#define BN   128
#define BKQ  32              // K-step (elements); row = 64 B
#define NKS  (C_ / BKQ)      // 16
#define NT_  (HW_ / BN)      // 18
#define MT_PER_BLOCK 3
#define MCHUNKS 6            // 18 m-tiles / 3
#define NSTEPS (MT_PER_BLOCK * NKS)   // 48 pipeline steps per block
#define TILE_SH (BM * BKQ)            // ushorts per tile (128 rows x 32)
#define BUF_SH  (3 * TILE_SH)         // ushorts per buffer (A0,A1,B)

typedef __bf16 bf16x8 __attribute__((ext_vector_type(8)));
typedef float  f32x4  __attribute__((ext_vector_type(4)));

__device__ __forceinline__ unsigned short f2bf(float f) {
  unsigned int u = __float_as_uint(f);
  u += 0x7FFF + ((u >> 16) & 1);   // round-to-nearest-even
  return (unsigned short)(u >> 16);
}

__device__ __forceinline__ void gload_lds16(const void* g, void* l) {
  __builtin_amdgcn_global_load_lds(
      (const __attribute__((address_space(1))) unsigned int*)g,
      (__attribute__((address_space(3))) unsigned int*)l, 16, 0, 0);
}

__global__ void zero_out(float* __restrict__ out, int n) {
  int i = blockIdx.x * 256 + threadIdx.x;
  if (i < n) out[i] = 0.0f;
}

// Fused: key fp32 [b][c][n] -> keyT bf16 [b][n][c], plus coarse partial dots
// (fp32, atomicAdd into pre-zeroed out channels 4..9).
__global__ void transpose_coarse(const float* __restrict__ key,
                                 const float* __restrict__ v0, const float* __restrict__ v1,
                                 const float* __restrict__ v2, const float* __restrict__ v3,
                                 const float* __restrict__ v4, const float* __restrict__ v5,
                                 unsigned short* __restrict__ keyT,
                                 float* __restrict__ out) {
  __shared__ float tile[32][33];
  __shared__ float red2[6][8][32];
  int b  = blockIdx.z;
  int n0 = blockIdx.x * 32;
  int c0 = blockIdx.y * 32;
  int tx = threadIdx.x;  // 0..31
  int ty = threadIdx.y;  // 0..7
#pragma unroll
  for (int i = 0; i < 4; i++) {
    int c = c0 + ty + i * 8;
    tile[ty + i * 8][tx] = key[(size_t)b * C_ * HW_ + (size_t)c * HW_ + n0 + tx];
  }
  __syncthreads();
#pragma unroll
  for (int i = 0; i < 4; i++) {
    int n = n0 + ty + i * 8;
    keyT[(size_t)b * HW_ * C_ + (size_t)n * C_ + c0 + tx] = f2bf(tile[tx][ty + i * 8]);
  }
  // coarse partials: thread covers n = n0+tx, c-range = c0 + ty*4 .. +4
  float s[6] = {0.f, 0.f, 0.f, 0.f, 0.f, 0.f};
#pragma unroll
  for (int i = 0; i < 4; i++) {
    int cr = ty * 4 + i;
    int c  = c0 + cr;
    float kv = tile[cr][tx];
    s[0] += v0[b * C_ + c] * kv;
    s[1] += v1[b * C_ + c] * kv;
    s[2] += v2[b * C_ + c] * kv;
    s[3] += v3[b * C_ + c] * kv;
    s[4] += v4[b * C_ + c] * kv;
    s[5] += v5[b * C_ + c] * kv;
  }
#pragma unroll
  for (int j = 0; j < 6; j++) red2[j][ty][tx] = s[j];
  __syncthreads();
  if (ty < 6) {
    float a = 0.f;
#pragma unroll
    for (int k = 0; k < 8; k++) a += red2[ty][k][tx];
    atomicAdd(&out[((size_t)b * 10 + 4 + ty) * HW_ + n0 + tx], a);
  }
}

// 4 fine banks fp32 [b][m][c] -> bf16 stacked [g][b][m][c]
__global__ void convert_banks(const float* __restrict__ b0, const float* __restrict__ b1,
                              const float* __restrict__ b2, const float* __restrict__ b3,
                              unsigned short* __restrict__ out) {
  const size_t per = (size_t)B_ * HW_ * C_;
  int g = blockIdx.y;
  const float* src = (g == 0) ? b0 : (g == 1) ? b1 : (g == 2) ? b2 : b3;
  size_t i = ((size_t)blockIdx.x * blockDim.x + threadIdx.x) * 4;
  float4 v = *(const float4*)(src + i);
  ushort4 o;
  o.x = f2bf(v.x); o.y = f2bf(v.y); o.z = f2bf(v.z); o.w = f2bf(v.w);
  *(ushort4*)(out + g * per + i) = o;
}

// Fine scores. 512 threads = 8 waves; wave w -> (bank = w&1, wm = ((w>>1)&1)*64,
// wn = (w>>2)*64). Per-wave acc is 4x4 f32x4 (64 regs) -> fits 128-reg cap at
// 4 waves/EU -> 2 blocks (16 waves) per CU.
// K-loop: 3-buffer LDS pipeline, ONE barrier per step, counted vmcnt(3)
// (never 0 in the loop). Stage for step s+2 is issued right after the barrier
// of step s -> every staged tile gets a 2-step latency window.
__global__ __launch_bounds__(512, 4) void fine_kernel(
    const unsigned short* __restrict__ keyT,   // bf16 [b][n][c]
    const unsigned short* __restrict__ banks,  // bf16 [g][b][m][c]
    const float* __restrict__ sds,             // fp32 [b][m][n]
    float* __restrict__ pmax) {
  int lin = blockIdx.x;
  int b   = lin & 7;               // XCD-pinned batch
  int ix  = lin >> 3;              // 0..215
  int gp  = (ix >= 108) ? 1 : 0;   // 0: banks 0,1 (unmasked)  1: banks 2,3 (masked)
  int w   = ix - gp * 108;         // 0..107
  int mc  = w / NT_;               // 0..5  (mc-major for A reuse in L2)
  int nt  = w % NT_;
  int n0  = nt * BN;

  __shared__ __align__(16) unsigned short sbuf[3][3][TILE_SH];  // 72 KB, 3-deep
  __shared__ float red[8][64];                                  // 2 KB

  int t    = threadIdx.x;
  int wave = t >> 6;               // 0..7
  int lane = t & 63;
  int quad = lane >> 4;
  int l15  = lane & 15;
  int bank_i = wave & 1;
  int wm   = ((wave >> 1) & 1) * 64;
  int wn   = (wave >> 2) * 64;

  // staging: wave-uniform LDS row base = wave*16; lane writes row
  // (rbase + lane>>2), 16B slot (lane&3). Source pre-swizzle so fragment
  // read slot = quad ^ ((row>>1)&3) returns k-chunk quad.
  int rbase = wave * 16;
  int ksub  = (lane & 3) ^ ((lane >> 3) & 3);   // global 8-elem chunk for this lane
  int swo   = (quad ^ ((l15 >> 1) & 3)) * 8;    // fragment-read element offset

  const unsigned short* bank0 = banks + ((size_t)(2 * gp) * B_ + b) * (size_t)HW_ * C_;
  const unsigned short* bank1 = banks + ((size_t)(2 * gp + 1) * B_ + b) * (size_t)HW_ * C_;
  const unsigned short* keyb  = keyT + (size_t)b * HW_ * C_;
  const float* maskb = sds + (size_t)b * HW_ * HW_;
  const bool masked = (gp == 1);

  // stage step s (s = mi*16 + kc) into buffer P: 3 gload_lds per wave.
  auto STAGE = [&](int P, int s) {
    int mi  = s >> 4;
    int kc  = s & 15;
    size_t m0s = (size_t)(mc * MT_PER_BLOCK + mi) * BM;
    unsigned short* dst = &sbuf[0][0][0] + P * BUF_SH + rbase * BKQ;
    size_t go = (size_t)(rbase + (lane >> 2)) * C_ + (size_t)kc * BKQ + ksub * 8;
    gload_lds16(bank0 + m0s * C_ + go, dst);
    gload_lds16(bank1 + m0s * C_ + go, dst + TILE_SH);
    gload_lds16(keyb + (size_t)n0 * C_ + go, dst + 2 * TILE_SH);
  };

  float rm[4];
#pragma unroll
  for (int i = 0; i < 4; i++) rm[i] = -3.4e38f;

  // prologue: fill two pipeline slots (6 loads outstanding per wave)
  STAGE(0, 0);
  STAGE(1, 1);

  for (int mi = 0; mi < MT_PER_BLOCK; mi++) {
    f32x4 acc[4][4];
#pragma unroll
    for (int i = 0; i < 4; i++)
#pragma unroll
      for (int j = 0; j < 4; j++)
#pragma unroll
        for (int e = 0; e < 4; e++) acc[i][j][e] = 0.0f;

    for (int kc = 0; kc < NKS; kc++) {
      int s = (mi << 4) | kc;
      // my stage(s) complete (only stage(s+1)'s 3 loads may remain in flight)
      if (s < NSTEPS - 1) asm volatile("s_waitcnt vmcnt(3)" ::: "memory");
      else                asm volatile("s_waitcnt vmcnt(0)" ::: "memory");
      // all waves' stage(s) complete; all reads of buf[(s+2)%3] (done at
      // step s-1, before each wave's lgkmcnt(0)+MFMA) are finished.
      __builtin_amdgcn_s_barrier();
      int sn = s + 2;
      if (sn < NSTEPS) STAGE(sn % 3, sn);

      const unsigned short* base  = &sbuf[0][0][0] + (s % 3) * BUF_SH;
      const unsigned short* Abase = base + bank_i * TILE_SH;
      const unsigned short* Bbase = base + 2 * TILE_SH;
      bf16x8 a[4], bv[4];
#pragma unroll
      for (int ms = 0; ms < 4; ms++)
        a[ms] = *(const bf16x8*)(Abase + (wm + ms * 16 + l15) * BKQ + swo);
#pragma unroll
      for (int ns = 0; ns < 4; ns++)
        bv[ns] = *(const bf16x8*)(Bbase + (wn + ns * 16 + l15) * BKQ + swo);
      asm volatile("s_waitcnt lgkmcnt(0)" ::: "memory");
      __builtin_amdgcn_sched_barrier(0);   // rule 18: keep MFMA below the wait

      __builtin_amdgcn_s_setprio(1);
#pragma unroll
      for (int ms = 0; ms < 4; ms++)
#pragma unroll
        for (int ns = 0; ns < 4; ns++)
          acc[ms][ns] = __builtin_amdgcn_mfma_f32_16x16x32_bf16(
              a[ms], bv[ns], acc[ms][ns], 0, 0, 0);
      __builtin_amdgcn_s_setprio(0);
    }

    int m0 = (mc * MT_PER_BLOCK + mi) * BM;
    // epilogue: lane holds S[m0+wm+ms*16+quad*4+r][n0+wn+ns*16+l15]
#pragma unroll
    for (int ms = 0; ms < 4; ms++) {
#pragma unroll
      for (int ns = 0; ns < 4; ns++) {
        int n = n0 + wn + ns * 16 + l15;
#pragma unroll
        for (int r = 0; r < 4; r++) {
          int m = m0 + wm + ms * 16 + quad * 4 + r;
          float s0 = acc[ms][ns][r];
          if (masked) {
            float w_ = maskb[(size_t)m * HW_ + n];
            s0 *= w_;
          }
          rm[ns] = fmaxf(rm[ns], s0);
        }
      }
    }
  }

  // reduce across quads (same column, different m rows within the wave)
#pragma unroll
  for (int ns = 0; ns < 4; ns++) {
    float v = rm[ns];
    v = fmaxf(v, __shfl_xor(v, 16, 64));
    v = fmaxf(v, __shfl_xor(v, 32, 64));
    rm[ns] = v;
  }
  if (lane < 16) {
#pragma unroll
    for (int ns = 0; ns < 4; ns++) red[wave][ns * 16 + l15] = rm[ns];
  }
  __syncthreads();
  // combine the two wm-halves: waves {bank + wnh*4} and {bank + 2 + wnh*4}
  if (t < 256) {
    int bank = t >> 7;         // 0..1
    int nn   = t & 127;        // 0..127
    int wnh  = nn >> 6;
    int nl   = nn & 63;
    float v = fmaxf(red[bank + wnh * 4][nl], red[bank + 2 + wnh * 4][nl]);
    pmax[(((size_t)mc * B_ + b) * 4 + 2 * gp + bank) * HW_ + n0 + nn] = v;
  }
}

// max over m-chunks -> out channels 0..3
__global__ void fine_combine(const float* __restrict__ pmax, float* __restrict__ out) {
  int i = blockIdx.x * 256 + threadIdx.x;   // over B_*4*HW_
  if (i >= B_ * 4 * HW_) return;
  int n = i % HW_;
  int g = (i / HW_) % 4;
  int b = i / (HW_ * 4);
  float v = -3.4e38f;
#pragma unroll
  for (int mc = 0; mc < MCHUNKS; mc++)
    v = fmaxf(v, pmax[(((size_t)mc * B_ + b) * 4 + g) * HW_ + n]);
  out[((size_t)b * 10 + g) * HW_ + n] = v;
}

extern "C" void kernel_launch(void* const* d_in, const int* in_sizes, int n_in,
                              void* d_out, int out_size, void* d_ws, size_t ws_size,
                              hipStream_t stream) {
  const float* key  = (const float*)d_in[0];
  const float* sds  = (const float*)d_in[1];
  const float* gbg  = (const float*)d_in[2];
  const float* gfg  = (const float*)d_in[3];
  const float* lbg  = (const float*)d_in[4];
  const float* lfg  = (const float*)d_in[5];
  const float* obg  = (const float*)d_in[6];
  const float* ofg  = (const float*)d_in[7];
  const float* sbg  = (const float*)d_in[8];
  const float* sfg  = (const float*)d_in[9];
  const float* lobg = (const float*)d_in[10];
  const float* lofg = (const float*)d_in[11];
  float* out = (float*)d_out;

  unsigned short* keyT  = (unsigned short*)d_ws;               // 18.9 MB
  unsigned short* banks = keyT + (size_t)B_ * HW_ * C_;        // +75.5 MB
  float* pmax = (float*)(banks + (size_t)4 * B_ * HW_ * C_);   // +1.77 MB

  zero_out<<<(out_size + 255) / 256, 256, 0, stream>>>(out, out_size);
  convert_banks<<<dim3((B_ * HW_ * C_) / (4 * 256), 4), 256, 0, stream>>>(gbg, gfg, lbg, lfg, banks);
  transpose_coarse<<<dim3(HW_ / 32, C_ / 32, B_), dim3(32, 8), 0, stream>>>(
      key, obg, ofg, sbg, sfg, lobg, lofg, keyT, out);
  fine_kernel<<<dim3(NT_ * MCHUNKS * 2 * B_), 512, 0, stream>>>(keyT, banks, sds, pmax);
  fine_combine<<<(B_ * 4 * HW_ + 255) / 256, 256, 0, stream>>>(pmax, out);
}

// Round 6
// 827.652 us; speedup vs baseline: 1.4070x; 1.0287x over previous
//
#include <hip/hip_runtime.h>

#define B_   8
#define C_   512
#define HW_  2304
#define BM   128
#define BN   128
#define BKQ  32              // K-step (elements); row = 64 B
#define NKS  (C_ / BKQ)      // 16
#define NT_  (HW_ / BN)      // 18
#define MT_PER_BLOCK 3
#define MCHUNKS 6            // 18 m-tiles / 3
#define NSTEPS (MT_PER_BLOCK * NKS)   // 48 pipeline steps per block
#define TILE_SH (BM * BKQ)            // ushorts per tile (128 rows x 32)
#define BUF_SH  (3 * TILE_SH)         // ushorts per buffer (A0,A1,B)

typedef __bf16 bf16x8 __attribute__((ext_vector_type(8)));
typedef float  f32x4  __attribute__((ext_vector_type(4)));

__device__ __forceinline__ unsigned short f2bf(float f) {
  unsigned int u = __float_as_uint(f);
  u += 0x7FFF + ((u >> 16) & 1);   // round-to-nearest-even
  return (unsigned short)(u >> 16);
}

__device__ __forceinline__ void gload_lds16(const void* g, void* l) {
  __builtin_amdgcn_global_load_lds(
      (const __attribute__((address_space(1))) unsigned int*)g,
      (__attribute__((address_space(3))) unsigned int*)l, 16, 0, 0);
}

__global__ void zero_out(float* __restrict__ out, int n) {
  int i = blockIdx.x * 256 + threadIdx.x;
  if (i < n) out[i] = 0.0f;
}

// Fused: key fp32 [b][c][n] -> keyT bf16 [b][n][c], plus coarse partial dots
// (fp32, atomicAdd into pre-zeroed out channels 4..9).
__global__ void transpose_coarse(const float* __restrict__ key,
                                 const float* __restrict__ v0, const float* __restrict__ v1,
                                 const float* __restrict__ v2, const float* __restrict__ v3,
                                 const float* __restrict__ v4, const float* __restrict__ v5,
                                 unsigned short* __restrict__ keyT,
                                 float* __restrict__ out) {
  __shared__ float tile[32][33];
  __shared__ float red2[6][8][32];
  int b  = blockIdx.z;
  int n0 = blockIdx.x * 32;
  int c0 = blockIdx.y * 32;
  int tx = threadIdx.x;  // 0..31
  int ty = threadIdx.y;  // 0..7
#pragma unroll
  for (int i = 0; i < 4; i++) {
    int c = c0 + ty + i * 8;
    tile[ty + i * 8][tx] = key[(size_t)b * C_ * HW_ + (size_t)c * HW_ + n0 + tx];
  }
  __syncthreads();
#pragma unroll
  for (int i = 0; i < 4; i++) {
    int n = n0 + ty + i * 8;
    keyT[(size_t)b * HW_ * C_ + (size_t)n * C_ + c0 + tx] = f2bf(tile[tx][ty + i * 8]);
  }
  // coarse partials: thread covers n = n0+tx, c-range = c0 + ty*4 .. +4
  float s[6] = {0.f, 0.f, 0.f, 0.f, 0.f, 0.f};
#pragma unroll
  for (int i = 0; i < 4; i++) {
    int cr = ty * 4 + i;
    int c  = c0 + cr;
    float kv = tile[cr][tx];
    s[0] += v0[b * C_ + c] * kv;
    s[1] += v1[b * C_ + c] * kv;
    s[2] += v2[b * C_ + c] * kv;
    s[3] += v3[b * C_ + c] * kv;
    s[4] += v4[b * C_ + c] * kv;
    s[5] += v5[b * C_ + c] * kv;
  }
#pragma unroll
  for (int j = 0; j < 6; j++) red2[j][ty][tx] = s[j];
  __syncthreads();
  if (ty < 6) {
    float a = 0.f;
#pragma unroll
    for (int k = 0; k < 8; k++) a += red2[ty][k][tx];
    atomicAdd(&out[((size_t)b * 10 + 4 + ty) * HW_ + n0 + tx], a);
  }
}

// 4 fine banks fp32 [b][m][c] -> bf16 stacked [g][b][m][c]
__global__ void convert_banks(const float* __restrict__ b0, const float* __restrict__ b1,
                              const float* __restrict__ b2, const float* __restrict__ b3,
                              unsigned short* __restrict__ out) {
  const size_t per = (size_t)B_ * HW_ * C_;
  int g = blockIdx.y;
  const float* src = (g == 0) ? b0 : (g == 1) ? b1 : (g == 2) ? b2 : b3;
  size_t i = ((size_t)blockIdx.x * blockDim.x + threadIdx.x) * 4;
  float4 v = *(const float4*)(src + i);
  ushort4 o;
  o.x = f2bf(v.x); o.y = f2bf(v.y); o.z = f2bf(v.z); o.w = f2bf(v.w);
  *(ushort4*)(out + g * per + i) = o;
}

// Fine scores. 512 threads = 8 waves; wave w -> (bank = w&1, wm = ((w>>1)&1)*64,
// wn = (w>>2)*64). Per-wave acc is 4x4 f32x4 (64 regs in AGPR half).
// __launch_bounds__(512,3): reg cap ~170 -> demand (~115) fits with slack,
// no spill.
// K-loop: 3-buffer LDS pipeline, ONE barrier per step, counted vmcnt(3)
// (never 0 in the loop). Stage for step s+2 is issued right after the barrier
// of step s -> every staged tile gets a 2-step latency window.
// NOTE: bank tiles advance with (mi, kc); the key tile advances with kc ONLY
// (offA vs offB — round-5 bug was applying offA to the key tile).
__global__ __launch_bounds__(512, 3) void fine_kernel(
    const unsigned short* __restrict__ keyT,   // bf16 [b][n][c]
    const unsigned short* __restrict__ banks,  // bf16 [g][b][m][c]
    const float* __restrict__ sds,             // fp32 [b][m][n]
    float* __restrict__ pmax) {
  int lin = blockIdx.x;
  int b   = lin & 7;               // XCD-pinned batch
  int ix  = lin >> 3;              // 0..215
  int gp  = (ix >= 108) ? 1 : 0;   // 0: banks 0,1 (unmasked)  1: banks 2,3 (masked)
  int w   = ix - gp * 108;         // 0..107
  int mc  = w / NT_;               // 0..5  (mc-major for A reuse in L2)
  int nt  = w % NT_;
  int n0  = nt * BN;

  __shared__ __align__(16) unsigned short sbuf[3][3][TILE_SH];  // 72 KB, 3-deep
  __shared__ float red[8][64];                                  // 2 KB

  int t    = threadIdx.x;
  int wave = t >> 6;               // 0..7
  int lane = t & 63;
  int quad = lane >> 4;
  int l15  = lane & 15;
  int bank_i = wave & 1;
  int wm   = ((wave >> 1) & 1) * 64;
  int wn   = (wave >> 2) * 64;

  // staging: wave-uniform LDS row base = wave*16; HW places lane i at
  // base + i*16B -> row (rbase + lane>>2), 16B slot (lane&3). Source
  // pre-swizzle so fragment read slot = quad ^ ((row>>1)&3) returns k-chunk.
  int rbase = wave * 16;
  int ksub  = (lane & 3) ^ ((lane >> 3) & 3);   // global 8-elem chunk for this lane
  int swo   = (quad ^ ((l15 >> 1) & 3)) * 8;    // fragment-read element offset

  const unsigned short* bank0 = banks + ((size_t)(2 * gp) * B_ + b) * (size_t)HW_ * C_;
  const unsigned short* bank1 = banks + ((size_t)(2 * gp + 1) * B_ + b) * (size_t)HW_ * C_;
  const unsigned short* keyb  = keyT + (size_t)b * HW_ * C_;
  const float* maskb = sds + (size_t)b * HW_ * HW_;
  const bool masked = (gp == 1);

  // loop-invariant per-lane offset + folded tile bases
  size_t lane_off = (size_t)(rbase + (lane >> 2)) * C_ + (size_t)ksub * 8;
  const unsigned short* a0p = bank0 + (size_t)mc * MT_PER_BLOCK * BM * C_ + lane_off;
  const unsigned short* a1p = bank1 + (size_t)mc * MT_PER_BLOCK * BM * C_ + lane_off;
  const unsigned short* kbp = keyb  + (size_t)n0 * C_ + lane_off;

  // stage step s (s = mi*16 + kc) into buffer P: 3 gload_lds per wave.
  auto STAGE = [&](int P, int s) {
    int offA = ((s >> 4) << 16) + ((s & 15) << 5);  // mi*BM*C_ + kc*BKQ (banks)
    int offB = (s & 15) << 5;                        // kc*BKQ only (key tile)
    unsigned short* dst = &sbuf[0][0][0] + P * BUF_SH + rbase * BKQ;
    gload_lds16(a0p + offA, dst);
    gload_lds16(a1p + offA, dst + TILE_SH);
    gload_lds16(kbp + offB, dst + 2 * TILE_SH);
  };

  float rm[4];
#pragma unroll
  for (int i = 0; i < 4; i++) rm[i] = -3.4e38f;

  // prologue: fill two pipeline slots (6 loads outstanding per wave)
  STAGE(0, 0);
  STAGE(1, 1);

  for (int mi = 0; mi < MT_PER_BLOCK; mi++) {
    f32x4 acc[4][4];
#pragma unroll
    for (int i = 0; i < 4; i++)
#pragma unroll
      for (int j = 0; j < 4; j++)
#pragma unroll
        for (int e = 0; e < 4; e++) acc[i][j][e] = 0.0f;

    for (int kc = 0; kc < NKS; kc++) {
      int s = (mi << 4) | kc;
      // my stage(s) complete (only stage(s+1)'s 3 loads may remain in flight)
      if (s < NSTEPS - 1) asm volatile("s_waitcnt vmcnt(3)" ::: "memory");
      else                asm volatile("s_waitcnt vmcnt(0)" ::: "memory");
      // all waves' stage(s) complete; all reads of buf[(s+2)%3] (done at
      // step s-1, before each wave's lgkmcnt(0)) are finished.
      __builtin_amdgcn_s_barrier();
      int sn = s + 2;
      if (sn < NSTEPS) STAGE(sn % 3, sn);

      const unsigned short* base  = &sbuf[0][0][0] + (s % 3) * BUF_SH;
      const unsigned short* Abase = base + bank_i * TILE_SH;
      const unsigned short* Bbase = base + 2 * TILE_SH;
      bf16x8 a[4], bv[4];
#pragma unroll
      for (int ms = 0; ms < 4; ms++)
        a[ms] = *(const bf16x8*)(Abase + (wm + ms * 16 + l15) * BKQ + swo);
#pragma unroll
      for (int ns = 0; ns < 4; ns++)
        bv[ns] = *(const bf16x8*)(Bbase + (wn + ns * 16 + l15) * BKQ + swo);
      asm volatile("s_waitcnt lgkmcnt(0)" ::: "memory");
      __builtin_amdgcn_sched_barrier(0);   // rule 18: keep MFMA below the wait

      __builtin_amdgcn_s_setprio(1);
#pragma unroll
      for (int ms = 0; ms < 4; ms++)
#pragma unroll
        for (int ns = 0; ns < 4; ns++)
          acc[ms][ns] = __builtin_amdgcn_mfma_f32_16x16x32_bf16(
              a[ms], bv[ns], acc[ms][ns], 0, 0, 0);
      __builtin_amdgcn_s_setprio(0);
    }

    int m0 = (mc * MT_PER_BLOCK + mi) * BM;
    // epilogue: lane holds S[m0+wm+ms*16+quad*4+r][n0+wn+ns*16+l15]
#pragma unroll
    for (int ms = 0; ms < 4; ms++) {
#pragma unroll
      for (int ns = 0; ns < 4; ns++) {
        int n = n0 + wn + ns * 16 + l15;
#pragma unroll
        for (int r = 0; r < 4; r++) {
          int m = m0 + wm + ms * 16 + quad * 4 + r;
          float s0 = acc[ms][ns][r];
          if (masked) {
            float w_ = maskb[(size_t)m * HW_ + n];
            s0 *= w_;
          }
          rm[ns] = fmaxf(rm[ns], s0);
        }
      }
    }
  }

  // reduce across quads (same column, different m rows within the wave)
#pragma unroll
  for (int ns = 0; ns < 4; ns++) {
    float v = rm[ns];
    v = fmaxf(v, __shfl_xor(v, 16, 64));
    v = fmaxf(v, __shfl_xor(v, 32, 64));
    rm[ns] = v;
  }
  if (lane < 16) {
#pragma unroll
    for (int ns = 0; ns < 4; ns++) red[wave][ns * 16 + l15] = rm[ns];
  }
  __syncthreads();
  // combine the two wm-halves: waves {bank + wnh*4} and {bank + 2 + wnh*4}
  if (t < 256) {
    int bank = t >> 7;         // 0..1
    int nn   = t & 127;        // 0..127
    int wnh  = nn >> 6;
    int nl   = nn & 63;
    float v = fmaxf(red[bank + wnh * 4][nl], red[bank + 2 + wnh * 4][nl]);
    pmax[(((size_t)mc * B_ + b) * 4 + 2 * gp + bank) * HW_ + n0 + nn] = v;
  }
}

// max over m-chunks -> out channels 0..3
__global__ void fine_combine(const float* __restrict__ pmax, float* __restrict__ out) {
  int i = blockIdx.x * 256 + threadIdx.x;   // over B_*4*HW_
  if (i >= B_ * 4 * HW_) return;
  int n = i % HW_;
  int g = (i / HW_) % 4;
  int b = i / (HW_ * 4);
  float v = -3.4e38f;
#pragma unroll
  for (int mc = 0; mc < MCHUNKS; mc++)
    v = fmaxf(v, pmax[(((size_t)mc * B_ + b) * 4 + g) * HW_ + n]);
  out[((size_t)b * 10 + g) * HW_ + n] = v;
}

extern "C" void kernel_launch(void* const* d_in, const int* in_sizes, int n_in,
                              void* d_out, int out_size, void* d_ws, size_t ws_size,
                              hipStream_t stream) {
  const float* key  = (const float*)d_in[0];
  const float* sds  = (const float*)d_in[1];
  const float* gbg  = (const float*)d_in[2];
  const float* gfg  = (const float*)d_in[3];
  const float* lbg  = (const float*)d_in[4];
  const float* lfg  = (const float*)d_in[5];
  const float* obg  = (const float*)d_in[6];
  const float* ofg  = (const float*)d_in[7];
  const float* sbg  = (const float*)d_in[8];
  const float* sfg  = (const float*)d_in[9];
  const float* lobg = (const float*)d_in[10];
  const float* lofg = (const float*)d_in[11];
  float* out = (float*)d_out;

  unsigned short* keyT  = (unsigned short*)d_ws;               // 18.9 MB
  unsigned short* banks = keyT + (size_t)B_ * HW_ * C_;        // +75.5 MB
  float* pmax = (float*)(banks + (size_t)4 * B_ * HW_ * C_);   // +1.77 MB

  zero_out<<<(out_size + 255) / 256, 256, 0, stream>>>(out, out_size);
  convert_banks<<<dim3((B_ * HW_ * C_) / (4 * 256), 4), 256, 0, stream>>>(gbg, gfg, lbg, lfg, banks);
  transpose_coarse<<<dim3(HW_ / 32, C_ / 32, B_), dim3(32, 8), 0, stream>>>(
      key, obg, ofg, sbg, sfg, lobg, lofg, keyT, out);
  fine_kernel<<<dim3(NT_ * MCHUNKS * 2 * B_), 512, 0, stream>>>(keyT, banks, sds, pmax);
  fine_combine<<<(B_ * 4 * HW_ + 255) / 256, 256, 0, stream>>>(pmax, out);
}

// Round 7
// 795.926 us; speedup vs baseline: 1.4631x; 1.0399x over previous
//
#include <hip/hip_runtime.h>

#define B_   8
#define C_   512
#define HW_  2304
#define BM   128
#define BN   64
#define BKQ  32              // K-step (elements); row = 64 B
#define NKS  (C_ / BKQ)      // 16
#define NT_  (HW_ / BN)      // 36
#define MT_PER_BLOCK 3
#define MCHUNKS 6            // 18 m-tiles / 3
#define NSTEPS (MT_PER_BLOCK * NKS)   // 48 pipeline steps per block
#define TILE_A_SH (BM * BKQ)          // 4096 ushorts (8 KB)
#define TILE_B_SH (BN * BKQ)          // 2048 ushorts (4 KB)
#define BUF_SH    (TILE_A_SH + TILE_B_SH)   // 6144 ushorts (12 KB)

typedef __bf16 bf16x8 __attribute__((ext_vector_type(8)));
typedef float  f32x4  __attribute__((ext_vector_type(4)));

__device__ __forceinline__ unsigned short f2bf(float f) {
  unsigned int u = __float_as_uint(f);
  u += 0x7FFF + ((u >> 16) & 1);   // round-to-nearest-even
  return (unsigned short)(u >> 16);
}

__device__ __forceinline__ void gload_lds16(const void* g, void* l) {
  __builtin_amdgcn_global_load_lds(
      (const __attribute__((address_space(1))) unsigned int*)g,
      (__attribute__((address_space(3))) unsigned int*)l, 16, 0, 0);
}

__global__ void zero_out(float* __restrict__ out, int n) {
  int i = blockIdx.x * 256 + threadIdx.x;
  if (i < n) out[i] = 0.0f;
}

// Fused: key fp32 [b][c][n] -> keyT bf16 [b][n][c], plus coarse partial dots
// (fp32, atomicAdd into pre-zeroed out channels 4..9).
__global__ void transpose_coarse(const float* __restrict__ key,
                                 const float* __restrict__ v0, const float* __restrict__ v1,
                                 const float* __restrict__ v2, const float* __restrict__ v3,
                                 const float* __restrict__ v4, const float* __restrict__ v5,
                                 unsigned short* __restrict__ keyT,
                                 float* __restrict__ out) {
  __shared__ float tile[32][33];
  __shared__ float red2[6][8][32];
  int b  = blockIdx.z;
  int n0 = blockIdx.x * 32;
  int c0 = blockIdx.y * 32;
  int tx = threadIdx.x;  // 0..31
  int ty = threadIdx.y;  // 0..7
#pragma unroll
  for (int i = 0; i < 4; i++) {
    int c = c0 + ty + i * 8;
    tile[ty + i * 8][tx] = key[(size_t)b * C_ * HW_ + (size_t)c * HW_ + n0 + tx];
  }
  __syncthreads();
#pragma unroll
  for (int i = 0; i < 4; i++) {
    int n = n0 + ty + i * 8;
    keyT[(size_t)b * HW_ * C_ + (size_t)n * C_ + c0 + tx] = f2bf(tile[tx][ty + i * 8]);
  }
  // coarse partials: thread covers n = n0+tx, c-range = c0 + ty*4 .. +4
  float s[6] = {0.f, 0.f, 0.f, 0.f, 0.f, 0.f};
#pragma unroll
  for (int i = 0; i < 4; i++) {
    int cr = ty * 4 + i;
    int c  = c0 + cr;
    float kv = tile[cr][tx];
    s[0] += v0[b * C_ + c] * kv;
    s[1] += v1[b * C_ + c] * kv;
    s[2] += v2[b * C_ + c] * kv;
    s[3] += v3[b * C_ + c] * kv;
    s[4] += v4[b * C_ + c] * kv;
    s[5] += v5[b * C_ + c] * kv;
  }
#pragma unroll
  for (int j = 0; j < 6; j++) red2[j][ty][tx] = s[j];
  __syncthreads();
  if (ty < 6) {
    float a = 0.f;
#pragma unroll
    for (int k = 0; k < 8; k++) a += red2[ty][k][tx];
    atomicAdd(&out[((size_t)b * 10 + 4 + ty) * HW_ + n0 + tx], a);
  }
}

// 4 fine banks fp32 [b][m][c] -> bf16 stacked [g][b][m][c]
__global__ void convert_banks(const float* __restrict__ b0, const float* __restrict__ b1,
                              const float* __restrict__ b2, const float* __restrict__ b3,
                              unsigned short* __restrict__ out) {
  const size_t per = (size_t)B_ * HW_ * C_;
  int g = blockIdx.y;
  const float* src = (g == 0) ? b0 : (g == 1) ? b1 : (g == 2) ? b2 : b3;
  size_t i = ((size_t)blockIdx.x * blockDim.x + threadIdx.x) * 4;
  float4 v = *(const float4*)(src + i);
  ushort4 o;
  o.x = f2bf(v.x); o.y = f2bf(v.y); o.z = f2bf(v.z); o.w = f2bf(v.w);
  *(ushort4*)(out + g * per + i) = o;
}

// Fine scores. 256 threads = 4 waves; wave w -> (wm = (w&1)*64, wn = (w>>1)*32).
// ONE bank per block (g = 0..3), BM=128 x BN=64 tile, acc[4][2] = 32 AGPR.
// Small state (unified ~116 regs) + 36.9 KB LDS -> 4 independent blocks/CU
// (16 waves): TLP across blocks fills the pipeline stalls that a single
// barrier-locked block cannot hide (round-6 lesson).
// K-loop: 3-buffer LDS pipeline, ONE barrier per step, counted vmcnt(3)
// (3 staging loads per wave per step; never drained to 0 in the loop).
__global__ __launch_bounds__(256, 4) void fine_kernel(
    const unsigned short* __restrict__ keyT,   // bf16 [b][n][c]
    const unsigned short* __restrict__ banks,  // bf16 [g][b][m][c]
    const float* __restrict__ sds,             // fp32 [b][m][n]
    float* __restrict__ pmax) {
  int lin = blockIdx.x;
  int b   = lin & 7;               // XCD-pinned batch
  int r   = lin >> 3;              // 0..863
  int mc  = r / (NT_ * 4);         // 0..5   (slowest: A-chunk reuse window)
  int r2  = r % (NT_ * 4);
  int nt  = r2 >> 2;               // 0..35
  int g   = r2 & 3;                // fastest: g=2,3 of same tile share sds in L2
  int n0  = nt * BN;

  __shared__ __align__(16) unsigned short sbuf[3][BUF_SH];  // 36 KB, 3-deep
  __shared__ float red[4][32];

  int t    = threadIdx.x;
  int wave = t >> 6;               // 0..3
  int lane = t & 63;
  int quad = lane >> 4;
  int l15  = lane & 15;
  int wm   = (wave & 1) * 64;
  int wn   = (wave >> 1) * 32;

  // staging: HW places lane i at LDS base + i*16B -> row (rowbase + lane>>2),
  // 16B slot (lane&3). Source pre-swizzle (ksub) so fragment read slot
  // = quad ^ ((l15>>1)&3) returns k-chunk quad; row bases are multiples of 16
  // so the swizzle phase is row&15-consistent.
  int ksub = (lane & 3) ^ ((lane >> 3) & 3);   // global 8-elem chunk for this lane
  int swo  = (quad ^ ((l15 >> 1) & 3)) * 8;    // fragment-read element offset

  const unsigned short* bankg = banks + ((size_t)g * B_ + b) * (size_t)HW_ * C_;
  const unsigned short* keyb  = keyT + (size_t)b * HW_ * C_;
  const float* maskb = sds + (size_t)b * HW_ * HW_;
  const bool masked = (g >= 2);

  // loop-invariant per-lane staging pointers
  size_t laneA = (size_t)(wave * 32 + (lane >> 2)) * C_ + (size_t)ksub * 8;
  size_t laneB = (size_t)(wave * 16 + (lane >> 2)) * C_ + (size_t)ksub * 8;
  const unsigned short* a0p = bankg + (size_t)mc * MT_PER_BLOCK * BM * C_ + laneA;
  const unsigned short* kbp = keyb + (size_t)n0 * C_ + laneB;

  // stage step s (s = mi*16 + kc) into buffer P: 3 gload_lds per wave
  // (A rows wave*32..+31 via two 16-row loads; B rows wave*16..+15).
  auto STAGE = [&](int P, int s) {
    int offA = ((s >> 4) << 16) + ((s & 15) << 5);  // mi*BM*C_ + kc*BKQ (bank)
    int offB = (s & 15) << 5;                        // kc*BKQ only (key tile)
    unsigned short* dst = &sbuf[P][0];
    gload_lds16(a0p + offA,           dst + (wave * 32) * BKQ);
    gload_lds16(a0p + offA + 16 * C_, dst + (wave * 32 + 16) * BKQ);
    gload_lds16(kbp + offB,           dst + TILE_A_SH + (wave * 16) * BKQ);
  };

  float rm[2];
  rm[0] = -3.4e38f; rm[1] = -3.4e38f;

  // prologue: fill two pipeline slots (6 loads outstanding per wave)
  STAGE(0, 0);
  STAGE(1, 1);

  for (int mi = 0; mi < MT_PER_BLOCK; mi++) {
    f32x4 acc[4][2];
#pragma unroll
    for (int i = 0; i < 4; i++)
#pragma unroll
      for (int j = 0; j < 2; j++)
#pragma unroll
        for (int e = 0; e < 4; e++) acc[i][j][e] = 0.0f;

    for (int kc = 0; kc < NKS; kc++) {
      int s = (mi << 4) | kc;
      // my stage(s) complete (only stage(s+1)'s 3 loads may remain in flight)
      if (s < NSTEPS - 1) asm volatile("s_waitcnt vmcnt(3)" ::: "memory");
      else                asm volatile("s_waitcnt vmcnt(0)" ::: "memory");
      // all waves' stage(s) writes landed; all reads of buf[(s+2)%3] (done at
      // step s-1 before each wave's lgkmcnt(0)) are finished.
      __builtin_amdgcn_s_barrier();
      int sn = s + 2;
      if (sn < NSTEPS) STAGE(sn % 3, sn);

      const unsigned short* Abase = &sbuf[s % 3][0];
      const unsigned short* Bbase = Abase + TILE_A_SH;
      bf16x8 a[4], bv[2];
#pragma unroll
      for (int ms = 0; ms < 4; ms++)
        a[ms] = *(const bf16x8*)(Abase + (wm + ms * 16 + l15) * BKQ + swo);
#pragma unroll
      for (int ns = 0; ns < 2; ns++)
        bv[ns] = *(const bf16x8*)(Bbase + (wn + ns * 16 + l15) * BKQ + swo);
      asm volatile("s_waitcnt lgkmcnt(0)" ::: "memory");
      __builtin_amdgcn_sched_barrier(0);   // rule 18: keep MFMA below the wait

      __builtin_amdgcn_s_setprio(1);
#pragma unroll
      for (int ms = 0; ms < 4; ms++)
#pragma unroll
        for (int ns = 0; ns < 2; ns++)
          acc[ms][ns] = __builtin_amdgcn_mfma_f32_16x16x32_bf16(
              a[ms], bv[ns], acc[ms][ns], 0, 0, 0);
      __builtin_amdgcn_s_setprio(0);
    }

    int m0 = (mc * MT_PER_BLOCK + mi) * BM;
    // epilogue: lane holds S[m0+wm+ms*16+quad*4+r][n0+wn+ns*16+l15]
#pragma unroll
    for (int ms = 0; ms < 4; ms++) {
#pragma unroll
      for (int ns = 0; ns < 2; ns++) {
        int n = n0 + wn + ns * 16 + l15;
#pragma unroll
        for (int rr = 0; rr < 4; rr++) {
          int m = m0 + wm + ms * 16 + quad * 4 + rr;
          float s0 = acc[ms][ns][rr];
          if (masked) {
            float w_ = maskb[(size_t)m * HW_ + n];
            s0 *= w_;
          }
          rm[ns] = fmaxf(rm[ns], s0);
        }
      }
    }
  }

  // reduce across quads (same column, different m rows within the wave)
#pragma unroll
  for (int ns = 0; ns < 2; ns++) {
    float v = rm[ns];
    v = fmaxf(v, __shfl_xor(v, 16, 64));
    v = fmaxf(v, __shfl_xor(v, 32, 64));
    rm[ns] = v;
  }
  if (lane < 16) {
#pragma unroll
    for (int ns = 0; ns < 2; ns++) red[wave][ns * 16 + l15] = rm[ns];
  }
  __syncthreads();
  // combine the two wm-halves: n-half h is covered by waves {2h, 2h+1}
  if (t < BN) {
    int wnh = t >> 5;
    int nl  = t & 31;
    float v = fmaxf(red[2 * wnh][nl], red[2 * wnh + 1][nl]);
    pmax[(((size_t)mc * B_ + b) * 4 + g) * HW_ + n0 + t] = v;
  }
}

// max over m-chunks -> out channels 0..3
__global__ void fine_combine(const float* __restrict__ pmax, float* __restrict__ out) {
  int i = blockIdx.x * 256 + threadIdx.x;   // over B_*4*HW_
  if (i >= B_ * 4 * HW_) return;
  int n = i % HW_;
  int g = (i / HW_) % 4;
  int b = i / (HW_ * 4);
  float v = -3.4e38f;
#pragma unroll
  for (int mc = 0; mc < MCHUNKS; mc++)
    v = fmaxf(v, pmax[(((size_t)mc * B_ + b) * 4 + g) * HW_ + n]);
  out[((size_t)b * 10 + g) * HW_ + n] = v;
}

extern "C" void kernel_launch(void* const* d_in, const int* in_sizes, int n_in,
                              void* d_out, int out_size, void* d_ws, size_t ws_size,
                              hipStream_t stream) {
  const float* key  = (const float*)d_in[0];
  const float* sds  = (const float*)d_in[1];
  const float* gbg  = (const float*)d_in[2];
  const float* gfg  = (const float*)d_in[3];
  const float* lbg  = (const float*)d_in[4];
  const float* lfg  = (const float*)d_in[5];
  const float* obg  = (const float*)d_in[6];
  const float* ofg  = (const float*)d_in[7];
  const float* sbg  = (const float*)d_in[8];
  const float* sfg  = (const float*)d_in[9];
  const float* lobg = (const float*)d_in[10];
  const float* lofg = (const float*)d_in[11];
  float* out = (float*)d_out;

  unsigned short* keyT  = (unsigned short*)d_ws;               // 18.9 MB
  unsigned short* banks = keyT + (size_t)B_ * HW_ * C_;        // +75.5 MB
  float* pmax = (float*)(banks + (size_t)4 * B_ * HW_ * C_);   // +1.77 MB

  zero_out<<<(out_size + 255) / 256, 256, 0, stream>>>(out, out_size);
  convert_banks<<<dim3((B_ * HW_ * C_) / (4 * 256), 4), 256, 0, stream>>>(gbg, gfg, lbg, lfg, banks);
  transpose_coarse<<<dim3(HW_ / 32, C_ / 32, B_), dim3(32, 8), 0, stream>>>(
      key, obg, ofg, sbg, sfg, lobg, lofg, keyT, out);
  fine_kernel<<<dim3(MCHUNKS * NT_ * 4 * B_), 256, 0, stream>>>(keyT, banks, sds, pmax);
  fine_combine<<<(B_ * 4 * HW_ + 255) / 256, 256, 0, stream>>>(pmax, out);
}